// Round 2
// baseline (670.586 us; speedup 1.0000x reference)
//
#include <hip/hip_runtime.h>
#include <hip/hip_bf16.h>

#define N_IMG 64
#define C_DIM 512
#define L_DIM 1024
#define KK 64
#define KG 65

// ---------------- Stage 1: per-position logits in registers ----------------
// Grid: (4 l-blocks, 64 images), Block: 256. Thread owns one position l.
// All 65 accumulators live in VGPRs; conv_w is read via wave-uniform (scalar)
// loads; x is read coalesced, double-buffered in registers. No LDS, no barriers.
__global__ __launch_bounds__(256) void k_logits(
    const float* __restrict__ x, const float* __restrict__ conv_w,
    const float* __restrict__ conv_b, float* __restrict__ aP,
    float* __restrict__ asum_part)
{
    const int lb = blockIdx.x;          // 0..3
    const int n  = blockIdx.y;          // 0..63
    const int t  = threadIdx.x;         // 0..255
    const int l  = lb * 256 + t;
    const int lane = t & 63;
    const int w    = t >> 6;

    const float* xp = x + (size_t)n * C_DIM * L_DIM + l;

    float acc[KG];
#pragma unroll
    for (int k = 0; k < KG; ++k) acc[k] = 0.f;
    float ss = 0.f;

    float xa[8], xb[8];

#define LOADC(buf, cc) { _Pragma("unroll") \
    for (int j = 0; j < 8; ++j) buf[j] = xp[(size_t)((cc) * 8 + j) * L_DIM]; }

#define FMAC(buf, cc) { _Pragma("unroll") \
    for (int j = 0; j < 8; ++j) ss += buf[j] * buf[j]; \
    _Pragma("unroll") \
    for (int k = 0; k < KG; ++k) { \
        _Pragma("unroll") \
        for (int j = 0; j < 8; ++j) \
            acc[k] += conv_w[(size_t)k * C_DIM + (cc) * 8 + j] * buf[j]; } }

    LOADC(xa, 0)
#pragma unroll 1
    for (int cc = 0; cc < 62; cc += 2) {
        LOADC(xb, cc + 1)
        FMAC(xa, cc)
        LOADC(xa, cc + 2)
        FMAC(xb, cc + 1)
    }
    LOADC(xb, 63)
    FMAC(xa, 62)
    FMAC(xb, 63)

    const float inv = 1.0f / fmaxf(sqrtf(ss), 1e-12f);

    // logits = acc*inv + conv_b ; softmax over 65 in registers
    float m = -1e30f;
#pragma unroll
    for (int k = 0; k < KG; ++k) {
        float lg = fmaf(acc[k], inv, conv_b[k]);
        acc[k] = lg;
        m = fmaxf(m, lg);
    }
    float s = 0.f;
#pragma unroll
    for (int k = 0; k < KG; ++k) {
        float e = expf(acc[k] - m);
        acc[k] = e;
        s += e;
    }
    const float rs = 1.0f / s;

    // write a' = a * inv ; wave-reduce a over lanes (=positions) for a_sum
#pragma unroll
    for (int k = 0; k < KK; ++k) {
        float aval = acc[k] * rs;
        aP[((size_t)(n * KK + k)) * L_DIM + l] = aval * inv;
        float ssum = aval;
#pragma unroll
        for (int off = 32; off; off >>= 1) ssum += __shfl_down(ssum, off, 64);
        if (lane == 0) asum_part[((size_t)n * 16 + lb * 4 + w) * KK + k] = ssum;
    }
}

// ---------------- a_sum reduce ----------------
__global__ void k_asum(const float* __restrict__ part, float* __restrict__ a_sum)
{
    int id = blockIdx.x * 256 + threadIdx.x;  // 4096 = 64n * 64k
    int n = id >> 6, k = id & 63;
    float s = 0.f;
#pragma unroll
    for (int p = 0; p < 16; ++p) s += part[((size_t)n * 16 + p) * KK + k];
    a_sum[id] = s;
}

// ---------------- Stage 2: weighted[n,k,c] partials over l-quarters ----------------
// Grid: (4 l-quarters, 2 c-tiles, 64 images), Block: 512. Lane owns 4 c's, wave owns 8 k's.
__global__ __launch_bounds__(512) void k_stage2(
    const float* __restrict__ x, const float* __restrict__ aP, float* __restrict__ wpart)
{
    __shared__ float xs[32 * 260];   // [l][c] padded, 33.3 KB
    __shared__ float as[KK * 32];    // [k][l] 8 KB

    const int lq = blockIdx.x;   // 0..3
    const int ct = blockIdx.y;   // 0..1
    const int n  = blockIdx.z;   // 0..63
    const int t = threadIdx.x, lane = t & 63, w = t >> 6;
    const int lbase = lq * 256;
    const int cbase = ct * 256;

    float acc[8][4] = {};

    for (int lc = 0; lc < 8; ++lc) {
        __syncthreads();
        // load x chunk: 256c x 32l (coalesced in l), transpose into [l][c]
#pragma unroll
        for (int i = 0; i < 16; ++i) {
            int idx = i * 512 + t;
            int cc = idx >> 5;      // 0..255
            int ll = idx & 31;
            xs[ll * 260 + cc] =
                x[((size_t)n * C_DIM + cbase + cc) * L_DIM + lbase + lc * 32 + ll];
        }
        // load a' chunk: 64k x 32l
#pragma unroll
        for (int i = 0; i < 4; ++i) {
            int idx = i * 512 + t;
            int kk2 = idx >> 5, ll = idx & 31;
            as[kk2 * 32 + ll] = aP[((size_t)n * KK + kk2) * L_DIM + lbase + lc * 32 + ll];
        }
        __syncthreads();
#pragma unroll
        for (int l4 = 0; l4 < 8; ++l4) {
            float4 av[8];
#pragma unroll
            for (int j = 0; j < 8; ++j)
                av[j] = *reinterpret_cast<const float4*>(&as[(w * 8 + j) * 32 + l4 * 4]);
#pragma unroll
            for (int r = 0; r < 4; ++r) {
                float4 xv = *reinterpret_cast<const float4*>(&xs[(l4 * 4 + r) * 260 + lane * 4]);
#pragma unroll
                for (int j = 0; j < 8; ++j) {
                    float a = (r == 0) ? av[j].x : (r == 1) ? av[j].y : (r == 2) ? av[j].z : av[j].w;
                    acc[j][0] += a * xv.x;
                    acc[j][1] += a * xv.y;
                    acc[j][2] += a * xv.z;
                    acc[j][3] += a * xv.w;
                }
            }
        }
    }
#pragma unroll
    for (int j = 0; j < 8; ++j) {
        int k = w * 8 + j;
        float4 v = make_float4(acc[j][0], acc[j][1], acc[j][2], acc[j][3]);
        *reinterpret_cast<float4*>(
            &wpart[(((size_t)n * 4 + lq) * KK + k) * C_DIM + cbase + lane * 4]) = v;
    }
}

// ---------------- reduce l-quarter partials ----------------
__global__ void k_wreduce(const float* __restrict__ wpart, float* __restrict__ wsum)
{
    size_t id = (size_t)blockIdx.x * 256 + threadIdx.x;  // 64*64*512 = 2,097,152
    size_t n = id >> 15;
    size_t rest = id & 32767;
    float s = 0.f;
#pragma unroll
    for (int q = 0; q < 4; ++q) s += wpart[n * 131072 + (size_t)q * 32768 + rest];
    wsum[id] = s;
}

// ---------------- per-(n,k) row sumsq of vlad ----------------
__global__ void k_rownorm(const float* __restrict__ wsum, const float* __restrict__ a_sum,
                          const float* __restrict__ cent, float* __restrict__ rn)
{
    int nk = blockIdx.x;          // 0..4095
    int k = nk & 63;
    int t = threadIdx.x;          // 256
    float as = a_sum[nk];
    float s = 0.f;
    for (int c = t; c < C_DIM; c += 256) {
        float v = wsum[(size_t)nk * C_DIM + c] - as * cent[(size_t)k * C_DIM + c];
        s += v * v;
    }
#pragma unroll
    for (int off = 32; off; off >>= 1) s += __shfl_down(s, off, 64);
    __shared__ float red[4];
    if ((t & 63) == 0) red[t >> 6] = s;
    __syncthreads();
    if (t == 0) rn[nk] = red[0] + red[1] + red[2] + red[3];
}

// ---------------- per-n global norm -> combined scale ----------------
__global__ void k_scale(const float* __restrict__ rn, float* __restrict__ scale)
{
    int n = blockIdx.x;     // 64
    int k = threadIdx.x;    // 64 = one wave
    float s = rn[n * 64 + k];
    float nrm = sqrtf(s);
    float den = fmaxf(nrm, 1e-12f);
    float tk = nrm / den;               // row-normalized row's norm (0 or 1)
    float tot = tk * tk;
#pragma unroll
    for (int off = 32; off; off >>= 1) tot += __shfl_down(tot, off, 64);
    tot = __shfl(tot, 0, 64);
    float g = fmaxf(sqrtf(tot), 1e-12f);
    scale[n * 64 + k] = 1.0f / (den * g);
}

// ---------------- final output ----------------
__global__ void k_out(const float* __restrict__ wsum, const float* __restrict__ a_sum,
                      const float* __restrict__ cent, const float* __restrict__ scale,
                      float* __restrict__ out)
{
    int nk = blockIdx.x;
    int k = nk & 63;
    int t = threadIdx.x;
    float as = a_sum[nk];
    float sc = scale[nk];
    for (int c = t; c < C_DIM; c += 256) {
        float v = wsum[(size_t)nk * C_DIM + c] - as * cent[(size_t)k * C_DIM + c];
        out[(size_t)nk * C_DIM + c] = v * sc;
    }
}

extern "C" void kernel_launch(void* const* d_in, const int* in_sizes, int n_in,
                              void* d_out, int out_size, void* d_ws, size_t ws_size,
                              hipStream_t stream)
{
    const float* x    = (const float*)d_in[0];
    const float* cent = (const float*)d_in[1];
    const float* cw   = (const float*)d_in[2];
    const float* cb   = (const float*)d_in[3];
    float* out = (float*)d_out;
    float* ws  = (float*)d_ws;

    float* aP        = ws;                                    // 64*64*1024
    float* asum_part = aP + (size_t)64 * 64 * 1024;           // 64*16*64
    float* a_sum     = asum_part + (size_t)64 * 16 * 64;      // 64*64
    float* wpart     = a_sum + 64 * 64;                       // 64*4*64*512
    float* weighted  = wpart + (size_t)64 * 4 * 64 * 512;     // 64*64*512
    float* rn        = weighted + (size_t)64 * 64 * 512;      // 64*64
    float* scale     = rn + 64 * 64;                          // 64*64

    k_logits<<<dim3(4, 64), 256, 0, stream>>>(x, cw, cb, aP, asum_part);
    k_asum<<<16, 256, 0, stream>>>(asum_part, a_sum);
    k_stage2<<<dim3(4, 2, 64), 512, 0, stream>>>(x, aP, wpart);
    k_wreduce<<<8192, 256, 0, stream>>>(wpart, weighted);
    k_rownorm<<<4096, 256, 0, stream>>>(weighted, a_sum, cent, rn);
    k_scale<<<64, 64, 0, stream>>>(rn, scale);
    k_out<<<4096, 256, 0, stream>>>(weighted, a_sum, cent, scale, out);
}

// Round 3
// 115.639 us; speedup vs baseline: 5.7989x; 5.7989x over previous
//
#include <hip/hip_runtime.h>
#include <hip/hip_bf16.h>

#define C_DIM 512
#define L_DIM 1024
#define KK 64
#define KG 65
#define KP 80   // padded k rows (5 tiles of 16)

using f32x4  = __attribute__((ext_vector_type(4))) float;
using bf16x8 = __attribute__((ext_vector_type(8))) short;

union U4 { uint4 u; bf16x8 b; };

__device__ __forceinline__ unsigned bfh(float x) { return __float_as_uint(x) >> 16; }
__device__ __forceinline__ float bfh_f(float x) { return __uint_as_float(__float_as_uint(x) & 0xFFFF0000u); }

// pack two fp32 -> word of 2 bf16 (truncation): low16 = a, high16 = b
__device__ __forceinline__ unsigned pack2(float a, float b) {
    return __builtin_amdgcn_perm(__float_as_uint(b), __float_as_uint(a), 0x07060302u);
}

// ---------------- prep: split conv_w into bf16 hi/lo, pad to 80 rows ----------------
__global__ void k_prep(const float* __restrict__ conv_w, const float* __restrict__ conv_b,
                       unsigned short* __restrict__ wtH, unsigned short* __restrict__ wtL,
                       float* __restrict__ wb)
{
    int k = blockIdx.x;           // 0..79
    int t = threadIdx.x;          // 0..255, 2 c's each
    for (int j = 0; j < 2; ++j) {
        int c = t * 2 + j;
        float v = (k < KG) ? conv_w[k * C_DIM + c] : 0.f;
        unsigned h = bfh(v);
        float r = v - __uint_as_float(h << 16);
        wtH[k * C_DIM + c] = (unsigned short)h;
        wtL[k * C_DIM + c] = (unsigned short)bfh(r);
    }
    if (t == 0) wb[k] = (k < KG) ? conv_b[k] : -1e30f;
}

// ---------------- Stage 1: MFMA logits + softmax -> aP (split bf16), asum partials ----
// Grid (8 l-blocks, 64 n), block 256 = 4 waves. Wave owns 32 l's (2 tiles of 16), all 5 k-tiles.
// Each wave stages its own 32l x 32c slice per chunk -> no barriers at all.
__global__ __launch_bounds__(256) void k_s1(
    const float* __restrict__ x, const unsigned short* __restrict__ wtH,
    const unsigned short* __restrict__ wtL, const float* __restrict__ wb,
    unsigned short* __restrict__ aPh, unsigned short* __restrict__ aPl,
    float* __restrict__ asum_part)
{
    __shared__ unsigned short xh[128 * 40];   // row l (128), 40-col pad (80B rows)
    __shared__ unsigned short xl[128 * 40];

    const int lb = blockIdx.x, n = blockIdx.y;
    const int t = threadIdx.x, lane = t & 63, w = t >> 6;
    const int lrel = lane & 31;          // l within wave's 32
    const int half = lane >> 5;          // c half (16 c's each)
    const int lw0 = lb * 128 + w * 32;   // global l base of wave
    const int lloc0 = w * 32;            // block-local l base

    const int arow = lane & 15;          // A row within tile
    const int agrp = lane >> 4;          // k-group for frags

    f32x4 acc[5][2];
#pragma unroll
    for (int a = 0; a < 5; ++a)
#pragma unroll
        for (int b = 0; b < 2; ++b) acc[a][b] = (f32x4)0.f;
    float ss = 0.f;

    for (int ch = 0; ch < 16; ++ch) {
        const int c0 = ch * 32;
        // ---- stage 32c x 32l (this wave's slice): 16 coalesced b32 loads/thread
        float xv[16];
#pragma unroll
        for (int j = 0; j < 16; ++j)
            xv[j] = x[(n * C_DIM + c0 + half * 16 + j) * L_DIM + lw0 + lrel];
#pragma unroll
        for (int j = 0; j < 16; ++j) ss += xv[j] * xv[j];
        // convert + pack + LDS write (b64)
#pragma unroll
        for (int jg = 0; jg < 4; ++jg) {
            float a0 = xv[jg * 4 + 0], a1 = xv[jg * 4 + 1], a2 = xv[jg * 4 + 2], a3 = xv[jg * 4 + 3];
            uint2 hw, lw;
            hw.x = pack2(a0, a1); hw.y = pack2(a2, a3);
            float r0 = a0 - bfh_f(a0), r1 = a1 - bfh_f(a1), r2 = a2 - bfh_f(a2), r3 = a3 - bfh_f(a3);
            lw.x = pack2(r0, r1); lw.y = pack2(r2, r3);
            int off = (lloc0 + lrel) * 40 + half * 16 + jg * 4;
            *reinterpret_cast<uint2*>(&xh[off]) = hw;
            *reinterpret_cast<uint2*>(&xl[off]) = lw;
        }
        // ---- A fragments (global, L2-resident)
        U4 ah[5], al[5];
#pragma unroll
        for (int kt = 0; kt < 5; ++kt) {
            int aoff = (kt * 16 + arow) * C_DIM + c0 + agrp * 8;
            ah[kt].u = *reinterpret_cast<const uint4*>(&wtH[aoff]);
            al[kt].u = *reinterpret_cast<const uint4*>(&wtL[aoff]);
        }
        // ---- B fragments (LDS b128)
        U4 bh[2], bl[2];
#pragma unroll
        for (int lt = 0; lt < 2; ++lt) {
            int boff = (lloc0 + lt * 16 + arow) * 40 + agrp * 8;
            bh[lt].u = *reinterpret_cast<const uint4*>(&xh[boff]);
            bl[lt].u = *reinterpret_cast<const uint4*>(&xl[boff]);
        }
        // ---- 4-product split MFMA
#pragma unroll
        for (int kt = 0; kt < 5; ++kt)
#pragma unroll
            for (int lt = 0; lt < 2; ++lt) {
                acc[kt][lt] = __builtin_amdgcn_mfma_f32_16x16x32_bf16(ah[kt].b, bh[lt].b, acc[kt][lt], 0, 0, 0);
                acc[kt][lt] = __builtin_amdgcn_mfma_f32_16x16x32_bf16(ah[kt].b, bl[lt].b, acc[kt][lt], 0, 0, 0);
                acc[kt][lt] = __builtin_amdgcn_mfma_f32_16x16x32_bf16(al[kt].b, bh[lt].b, acc[kt][lt], 0, 0, 0);
                acc[kt][lt] = __builtin_amdgcn_mfma_f32_16x16x32_bf16(al[kt].b, bl[lt].b, acc[kt][lt], 0, 0, 0);
            }
    }

    // ---- per-l inverse norm (lanes 0..31 & 32..63 hold halves of same l)
    ss += __shfl_xor(ss, 32, 64);
    const float inv = 1.0f / fmaxf(sqrtf(ss), 1e-12f);
    float invc[2];
#pragma unroll
    for (int lt = 0; lt < 2; ++lt) invc[lt] = __shfl(inv, lt * 16 + arow, 64);

    // ---- bias
    float4 wbv[5];
#pragma unroll
    for (int kt = 0; kt < 5; ++kt)
        wbv[kt] = *reinterpret_cast<const float4*>(&wb[kt * 16 + agrp * 4]);

    // ---- softmax per l (values spread over lanes {l, l+16, l+32, l+48})
    float aval[5][2][4];
    float rs[2], Mv[2];
#pragma unroll
    for (int lt = 0; lt < 2; ++lt) {
        float m = -1e30f;
#pragma unroll
        for (int kt = 0; kt < 5; ++kt)
#pragma unroll
            for (int r = 0; r < 4; ++r) {
                float lg = acc[kt][lt][r] * invc[lt] + ((const float*)&wbv[kt])[r];
                aval[kt][lt][r] = lg;
                m = fmaxf(m, lg);
            }
        m = fmaxf(m, __shfl_xor(m, 16, 64));
        m = fmaxf(m, __shfl_xor(m, 32, 64));
        Mv[lt] = m;
        float s = 0.f;
#pragma unroll
        for (int kt = 0; kt < 5; ++kt)
#pragma unroll
            for (int r = 0; r < 4; ++r) {
                float e = __expf(aval[kt][lt][r] - m);
                aval[kt][lt][r] = e;
                s += e;
            }
        s += __shfl_xor(s, 16, 64);
        s += __shfl_xor(s, 32, 64);
        rs[lt] = 1.0f / s;
    }

    // ---- a_sum partials + aP (= a*inv) as split bf16
#pragma unroll
    for (int kt = 0; kt < 4; ++kt)
#pragma unroll
        for (int r = 0; r < 4; ++r) {
            int k = kt * 16 + agrp * 4 + r;
            float s01 = 0.f;
#pragma unroll
            for (int lt = 0; lt < 2; ++lt) {
                float a = aval[kt][lt][r] * rs[lt];
                aval[kt][lt][r] = a;
                s01 += a;
            }
#pragma unroll
            for (int off = 8; off; off >>= 1) s01 += __shfl_xor(s01, off, 64);
            if ((lane & 15) == 0)
                asum_part[((n * 8 + lb) * 4 + w) * KK + k] = s01;
#pragma unroll
            for (int lt = 0; lt < 2; ++lt) {
                float ap = aval[kt][lt][r] * invc[lt];
                unsigned h = bfh(ap);
                float res = ap - __uint_as_float(h << 16);
                int idx = (n * KK + k) * L_DIM + lw0 + lt * 16 + arow;
                aPh[idx] = (unsigned short)h;
                aPl[idx] = (unsigned short)bfh(res);
            }
        }
    (void)Mv;
}

// ---------------- a_sum reduce (32 partials) ----------------
__global__ void k_asum(const float* __restrict__ part, float* __restrict__ a_sum)
{
    int id = blockIdx.x * 256 + threadIdx.x;  // 4096
    int n = id >> 6, k = id & 63;
    float s = 0.f;
#pragma unroll
    for (int p = 0; p < 32; ++p) s += part[(n * 32 + p) * KK + k];
    a_sum[id] = s;
}

// ---------------- Stage 2: weighted = a' x^T via MFMA (no LDS) ----------------
// Grid (2 l-halves, 4 c-quarters, 64 n), block 256 = 4 waves; wave owns 32 c (2 tiles), all 4 k-tiles.
__global__ __launch_bounds__(256) void k_s2(
    const float* __restrict__ x, const unsigned short* __restrict__ aPh,
    const unsigned short* __restrict__ aPl, float* __restrict__ wpart)
{
    const int lq = blockIdx.x, cq = blockIdx.y, n = blockIdx.z;
    const int t = threadIdx.x, lane = t & 63, w = t >> 6;
    const int arow = lane & 15, agrp = lane >> 4;
    const int cb = cq * 128 + w * 32;

    f32x4 acc[4][2];
#pragma unroll
    for (int a = 0; a < 4; ++a)
#pragma unroll
        for (int b = 0; b < 2; ++b) acc[a][b] = (f32x4)0.f;

    for (int ch = 0; ch < 16; ++ch) {
        const int l0 = lq * 512 + ch * 32;
        U4 ah[4], al[4];
#pragma unroll
        for (int kt = 0; kt < 4; ++kt) {
            int aoff = (n * KK + kt * 16 + arow) * L_DIM + l0 + agrp * 8;
            ah[kt].u = *reinterpret_cast<const uint4*>(&aPh[aoff]);
            al[kt].u = *reinterpret_cast<const uint4*>(&aPl[aoff]);
        }
        U4 bh[2], bl[2];
#pragma unroll
        for (int ct = 0; ct < 2; ++ct) {
            int c = cb + ct * 16 + arow;
            const float4 v0 = *reinterpret_cast<const float4*>(&x[(n * C_DIM + c) * L_DIM + l0 + agrp * 8]);
            const float4 v1 = *reinterpret_cast<const float4*>(&x[(n * C_DIM + c) * L_DIM + l0 + agrp * 8 + 4]);
            bh[ct].u.x = pack2(v0.x, v0.y); bh[ct].u.y = pack2(v0.z, v0.w);
            bh[ct].u.z = pack2(v1.x, v1.y); bh[ct].u.w = pack2(v1.z, v1.w);
            float r0 = v0.x - bfh_f(v0.x), r1 = v0.y - bfh_f(v0.y);
            float r2 = v0.z - bfh_f(v0.z), r3 = v0.w - bfh_f(v0.w);
            float r4 = v1.x - bfh_f(v1.x), r5 = v1.y - bfh_f(v1.y);
            float r6 = v1.z - bfh_f(v1.z), r7 = v1.w - bfh_f(v1.w);
            bl[ct].u.x = pack2(r0, r1); bl[ct].u.y = pack2(r2, r3);
            bl[ct].u.z = pack2(r4, r5); bl[ct].u.w = pack2(r6, r7);
        }
#pragma unroll
        for (int kt = 0; kt < 4; ++kt)
#pragma unroll
            for (int ct = 0; ct < 2; ++ct) {
                acc[kt][ct] = __builtin_amdgcn_mfma_f32_16x16x32_bf16(ah[kt].b, bh[ct].b, acc[kt][ct], 0, 0, 0);
                acc[kt][ct] = __builtin_amdgcn_mfma_f32_16x16x32_bf16(ah[kt].b, bl[ct].b, acc[kt][ct], 0, 0, 0);
                acc[kt][ct] = __builtin_amdgcn_mfma_f32_16x16x32_bf16(al[kt].b, bh[ct].b, acc[kt][ct], 0, 0, 0);
            }
    }
#pragma unroll
    for (int kt = 0; kt < 4; ++kt)
#pragma unroll
        for (int ct = 0; ct < 2; ++ct)
#pragma unroll
            for (int r = 0; r < 4; ++r) {
                int k = kt * 16 + agrp * 4 + r;
                int c = cb + ct * 16 + arow;
                wpart[((lq * 64 + n) * KK + k) * C_DIM + c] = acc[kt][ct][r];
            }
}

// ---------------- per-(n,k) row sumsq of vlad ----------------
__global__ void k_rownorm(const float* __restrict__ wpart, const float* __restrict__ a_sum,
                          const float* __restrict__ cent, float* __restrict__ rn)
{
    int nk = blockIdx.x;          // 0..4095
    int k = nk & 63;
    int t = threadIdx.x;          // 256
    float as = a_sum[nk];
    float s = 0.f;
    for (int c = t; c < C_DIM; c += 256) {
        float v = wpart[nk * C_DIM + c] + wpart[2097152 + nk * C_DIM + c] - as * cent[k * C_DIM + c];
        s += v * v;
    }
#pragma unroll
    for (int off = 32; off; off >>= 1) s += __shfl_down(s, off, 64);
    __shared__ float red[4];
    if ((t & 63) == 0) red[t >> 6] = s;
    __syncthreads();
    if (t == 0) rn[nk] = red[0] + red[1] + red[2] + red[3];
}

// ---------------- per-n global norm -> combined scale ----------------
__global__ void k_scale(const float* __restrict__ rn, float* __restrict__ scale)
{
    int n = blockIdx.x;
    int k = threadIdx.x;    // 64
    float s = rn[n * 64 + k];
    float nrm = sqrtf(s);
    float den = fmaxf(nrm, 1e-12f);
    float tk = nrm / den;
    float tot = tk * tk;
#pragma unroll
    for (int off = 32; off; off >>= 1) tot += __shfl_down(tot, off, 64);
    tot = __shfl(tot, 0, 64);
    float g = fmaxf(sqrtf(tot), 1e-12f);
    scale[n * 64 + k] = 1.0f / (den * g);
}

// ---------------- final output ----------------
__global__ void k_out(const float* __restrict__ wpart, const float* __restrict__ a_sum,
                      const float* __restrict__ cent, const float* __restrict__ scale,
                      float* __restrict__ out)
{
    int nk = blockIdx.x;
    int k = nk & 63;
    int t = threadIdx.x;
    float as = a_sum[nk];
    float sc = scale[nk];
    for (int c = t; c < C_DIM; c += 256) {
        float v = wpart[nk * C_DIM + c] + wpart[2097152 + nk * C_DIM + c] - as * cent[k * C_DIM + c];
        out[nk * C_DIM + c] = v * sc;
    }
}

extern "C" void kernel_launch(void* const* d_in, const int* in_sizes, int n_in,
                              void* d_out, int out_size, void* d_ws, size_t ws_size,
                              hipStream_t stream)
{
    const float* x    = (const float*)d_in[0];
    const float* cent = (const float*)d_in[1];
    const float* cw   = (const float*)d_in[2];
    const float* cb   = (const float*)d_in[3];
    float* out = (float*)d_out;
    char* ws = (char*)d_ws;

    unsigned short* wtH = (unsigned short*)(ws + 0);                // 80 KB
    unsigned short* wtL = (unsigned short*)(ws + 131072);           // 80 KB
    float*          wb  = (float*)(ws + 262144);                    // 320 B
    unsigned short* aPh = (unsigned short*)(ws + 524288);           // 8 MB
    unsigned short* aPl = (unsigned short*)(ws + 8912896);          // 8 MB
    float* asum_part    = (float*)(ws + 17301504);                  // 512 KB
    float* a_sum        = (float*)(ws + 17825792);                  // 16 KB
    float* wpart        = (float*)(ws + 18874368);                  // 16 MB (2 halves)
    float* rn           = (float*)(ws + 35651584);
    float* scale        = (float*)(ws + 35667968);

    k_prep<<<KP, 256, 0, stream>>>(cw, cb, wtH, wtL, wb);
    k_s1<<<dim3(8, 64), 256, 0, stream>>>(x, wtH, wtL, wb, aPh, aPl, asum_part);
    k_asum<<<16, 256, 0, stream>>>(asum_part, a_sum);
    k_s2<<<dim3(2, 4, 64), 256, 0, stream>>>(x, aPh, aPl, wpart);
    k_rownorm<<<4096, 256, 0, stream>>>(wpart, a_sum, cent, rn);
    k_scale<<<64, 64, 0, stream>>>(rn, scale);
    k_out<<<4096, 256, 0, stream>>>(wpart, a_sum, cent, scale, out);
}